// Round 5
// baseline (164.855 us; speedup 1.0000x reference)
//
#include <hip/hip_runtime.h>

#define HW    16384   // 128*128
#define Wh    128
#define Cin   64
#define C2    32
#define HW4   4096    // 64*64

typedef short short8 __attribute__((ext_vector_type(8)));     // 8 bf16 = 4 VGPRs
typedef float float4v __attribute__((ext_vector_type(4)));
typedef unsigned uint4v __attribute__((ext_vector_type(4)));

#define LOG2E 1.44269504f
#define OFFE  43.2808512f   // 30*log2(e): exp(s-30) == exp2(s*log2e - OFFE)

__device__ __forceinline__ unsigned pack2bf16(float lo, float hi) {
  unsigned ul = __builtin_bit_cast(unsigned, lo);
  unsigned uh = __builtin_bit_cast(unsigned, hi);
  ul = (ul + 0x7fffu + ((ul >> 16) & 1u)) >> 16;
  uh = (uh + 0x7fffu + ((uh >> 16) & 1u)) & 0xffff0000u;
  return ul | uh;
}
__device__ __forceinline__ unsigned short f2bf(float f) {
  unsigned u = __builtin_bit_cast(unsigned, f);
  return (unsigned short)((u + 0x7fffu + ((u >> 16) & 1u)) >> 16);
}
// RTZ-truncate two fp32 to bf16, lo in [15:0], hi in [31:16]
__device__ __forceinline__ unsigned packtrunc(float lo, float hi) {
  return __builtin_amdgcn_perm(__builtin_bit_cast(unsigned, hi),
                               __builtin_bit_cast(unsigned, lo), 0x07060302u);
}

// ---------------------------------------------------------------------------
// Kernel 0: weight repack. wAll[og][c][24] = {theta(8, x log2e), phi(8), g(8)}
// ---------------------------------------------------------------------------
__global__ __launch_bounds__(256) void repack_w_kern(
    const float* __restrict__ wt, const float* __restrict__ bt,
    const float* __restrict__ wp, const float* __restrict__ bp,
    const float* __restrict__ wg, const float* __restrict__ bg,
    float* __restrict__ wAll, float* __restrict__ bAll) {
  int idx = blockIdx.x * 256 + threadIdx.x;
  if (idx < 6144) {
    int og = idx / 1536, rem = idx % 1536;
    int c = rem / 24, j = rem % 24;
    int o = og * 8 + (j & 7);
    float v;
    if (j < 8)       v = wt[o * Cin + c] * LOG2E;
    else if (j < 16) v = wp[o * Cin + c];
    else             v = wg[o * Cin + c];
    wAll[idx] = v;
  } else if (idx < 6240) {
    int i2 = idx - 6144;
    int og = i2 / 24, j = i2 % 24;
    int o = og * 8 + (j & 7);
    bAll[i2] = (j < 8) ? bt[o] * LOG2E : (j < 16 ? bp[o] : bg[o]);
  }
}

// ---------------------------------------------------------------------------
// Kernel 1: FUSED theta+phi+g conv (+2x2 maxpool) with LDS-STAGED x.
// (unchanged this round)
// ---------------------------------------------------------------------------
__global__ __launch_bounds__(256) void conv_qkv_kern(
    const float* __restrict__ x, const float* __restrict__ wAll,
    const float* __restrict__ bAll, unsigned short* __restrict__ Q,
    unsigned short* __restrict__ K, unsigned short* __restrict__ Vt) {
  __shared__ float smX[2][8][256];               // 16 KB, double-buffered
  __shared__ unsigned short smV[8][64];          // 1 KB
  int tid = threadIdx.x;
  int og = blockIdx.y, bz = blockIdx.z;
  int pxbase = blockIdx.x * 2 * Wh;              // full-res rows 2i, 2i+1
  int jloc = tid >> 2;                           // pooled col 0..63
  int rpar = (tid >> 1) & 1, cpar = tid & 1;
  int myPx = rpar * Wh + 2 * jloc + cpar;        // local pixel 0..255
  const float* xb = x + (size_t)bz * Cin * HW + pxbase;
  const float* wc = wAll + og * 1536;            // uniform -> s_load
  const float* bb = bAll + og * 24;

  // stage chunk: 512 float4 = 256 threads x 2; ch = f>>6, p4 = f&63
  auto stage = [&](int cb8, int buf) {
#pragma unroll
    for (int u = 0; u < 2; ++u) {
      int f = u * 256 + tid;
      int ch = f >> 6, p4 = f & 63;
      *(float4*)&smX[buf][ch][p4 * 4] =
          *(const float4*)(xb + (size_t)(cb8 * 8 + ch) * HW + p4 * 4);
    }
  };

  float acc[24];
#pragma unroll
  for (int k = 0; k < 24; ++k) acc[k] = bb[k];

  stage(0, 0);
  __syncthreads();
  for (int cb8 = 0; cb8 < 8; ++cb8) {
    if (cb8 < 7) stage(cb8 + 1, (cb8 + 1) & 1);  // loads fly over compute
    float xv[8];
#pragma unroll
    for (int u = 0; u < 8; ++u) xv[u] = smX[cb8 & 1][u][myPx];
#pragma unroll
    for (int u = 0; u < 8; ++u) {
#pragma unroll
      for (int k = 0; k < 24; ++k)
        acc[k] = fmaf(wc[(cb8 * 8 + u) * 24 + k], xv[u], acc[k]);
    }
    __syncthreads();                             // staged buf ready for next
  }

  int pp = blockIdx.x * 64 + jloc;               // global pooled pixel
  int p = pxbase + myPx;                         // global full-res pixel
  // theta -> Q
  {
    uint4 up;
    up.x = pack2bf16(acc[0], acc[1]); up.y = pack2bf16(acc[2], acc[3]);
    up.z = pack2bf16(acc[4], acc[5]); up.w = pack2bf16(acc[6], acc[7]);
    *(uint4*)(Q + ((size_t)bz * HW + p) * C2 + og * 8) = up;
  }
  // 2x2 maxpool across lane-mates {4j..4j+3}
  float aP[8], aG[8];
#pragma unroll
  for (int o = 0; o < 8; ++o) {
    float vp = acc[8 + o], vg = acc[16 + o];
    vp = fmaxf(vp, __shfl_xor(vp, 1)); vp = fmaxf(vp, __shfl_xor(vp, 2));
    vg = fmaxf(vg, __shfl_xor(vg, 1)); vg = fmaxf(vg, __shfl_xor(vg, 2));
    aP[o] = vp; aG[o] = vg;
  }
  if ((tid & 3) == 0) {
    int loc = pp & 31, tile = pp >> 5;
    int prow = ((loc & 4) << 2) + ((loc >> 3) << 2) + (loc & 3);   // S^T perm
    uint4 up;
    up.x = pack2bf16(aP[0], aP[1]); up.y = pack2bf16(aP[2], aP[3]);
    up.z = pack2bf16(aP[4], aP[5]); up.w = pack2bf16(aP[6], aP[7]);
    *(uint4*)(K + ((size_t)bz * HW4 + tile * 32 + prow) * C2 + og * 8) = up;
#pragma unroll
    for (int o = 0; o < 8; ++o) smV[o][tid >> 2] = f2bf(aG[o]);
  }
  __syncthreads();
  // coalesced V store: thread t -> channel t>>5, dword t&31 (2 keys)
  {
    int ch = tid >> 5, idx = tid & 31;
    unsigned v = ((unsigned*)smV)[ch * 32 + idx];
    *(unsigned*)(Vt + (size_t)bz * C2 * HW4 + (size_t)(og * 8 + ch) * HW4 +
                 blockIdx.x * 64 + 2 * idx) = v;
  }
}

// ---------------------------------------------------------------------------
// Kernel 2: MFMA flash attention + FUSED OUTPUT CONV (R17).
// Main loop = EXACT R12 body (best measured, 59.3 µs; R13/R14/R15/R16 probes
// all neutral-or-worse -> plateau accepted).
// R16 post-mortem: non-attn time is stable ~100 µs across all rounds while
// the convs' roofline says ~15 µs -> the gap is kernel count (launch/drain
// ~10 µs each) + the Y round-trip. Fusion: the merge epilogue already has
// the normalized 64x32 y-tile in LDS (smY) -> do the 32->64 conv + bias +
// residual right here. Removes: conv_out kernel + gap, Y write (8 MB),
// Y read (8 MB), x re-read (16.8 MB). Adds ~512 FMA + 32 ds_read per
// thread. Conv arithmetic keeps conv_out's exact fp32 order (bias, then
// o=0..31 fmaf) and y passes through fp32 LDS -> bitwise-identical output.
// Epilogue layout: wave wv -> out-channels wv*16..+15; lane = pixel ->
// x/out 256B-contiguous per instruction; smY reads (px*33+c)%32 = 2-way
// bank = free; w_out wave-uniform -> s_load.
// ---------------------------------------------------------------------------
__global__ __launch_bounds__(256, 4) void attn_mfma_kern(
    const unsigned short* __restrict__ Qb, const unsigned short* __restrict__ Kb,
    const unsigned short* __restrict__ Vt, const float* __restrict__ x,
    const float* __restrict__ w_out, const float* __restrict__ b_out,
    float* __restrict__ out) {
  __shared__ float smY[3][64][33];   // 25.3 KB
  __shared__ float smL[4][64];       // 1 KB
  int lane = threadIdx.x & 63;
  int wv = threadIdx.x >> 6;
  int quad = lane >> 4, l16 = lane & 15;
  int bz = blockIdx.y;
  int qrow0 = blockIdx.x * 64;

  short8 qf[4];
#pragma unroll
  for (int f = 0; f < 4; ++f)
    qf[f] = *(const short8*)(Qb + ((size_t)bz * HW + qrow0 + f * 16 + l16) * C2 + quad * 8);
  const unsigned short* kb = Kb + ((size_t)bz * HW4 + wv * 1024) * C2;
  const unsigned short* vb = Vt + (size_t)bz * C2 * HW4 + wv * 1024;

  short8 ones;
#pragma unroll
  for (int i = 0; i < 8; ++i) ones[i] = (short)0x3F80;  // bf16 1.0

  float4v z = {0.f, 0.f, 0.f, 0.f};
  float4v ya[4] = {z, z, z, z};   // y cols l16 (ch 0..15)
  float4v yh[4] = {z, z, z, z};   // y cols 16+l16
  float4v y2[4] = {z, z, z, z};   // row sums l (ones-MFMA)
  float4v moff = {-OFFE, -OFFE, -OFFE, -OFFE};

  for (int t = 0; t < 32; ++t) {
    const unsigned short* kt = kb + (size_t)t * 32 * C2;
    const unsigned short* vt = vb + t * 32;
    short8 ka = *(const short8*)(kt + (size_t)l16 * C2 + quad * 8);
    short8 kh = *(const short8*)(kt + (size_t)(16 + l16) * C2 + quad * 8);
    short8 va = *(const short8*)(vt + (size_t)l16 * HW4 + quad * 8);
    short8 vh = *(const short8*)(vt + (size_t)(16 + l16) * HW4 + quad * 8);
#pragma unroll
    for (int f = 0; f < 4; ++f) {
      float4v sa = __builtin_amdgcn_mfma_f32_16x16x32_bf16(ka, qf[f], moff, 0, 0, 0);
      float4v sh = __builtin_amdgcn_mfma_f32_16x16x32_bf16(kh, qf[f], moff, 0, 0, 0);
      float e0 = __builtin_amdgcn_exp2f(sa[0]), e1 = __builtin_amdgcn_exp2f(sa[1]);
      float e2 = __builtin_amdgcn_exp2f(sa[2]), e3 = __builtin_amdgcn_exp2f(sa[3]);
      float g0 = __builtin_amdgcn_exp2f(sh[0]), g1 = __builtin_amdgcn_exp2f(sh[1]);
      float g2 = __builtin_amdgcn_exp2f(sh[2]), g3 = __builtin_amdgcn_exp2f(sh[3]);
      uint4v d = {packtrunc(e0, e1), packtrunc(e2, e3),
                  packtrunc(g0, g1), packtrunc(g2, g3)};
      short8 pf = __builtin_bit_cast(short8, d);
      ya[f] = __builtin_amdgcn_mfma_f32_16x16x32_bf16(pf, va,   ya[f], 0, 0, 0);
      yh[f] = __builtin_amdgcn_mfma_f32_16x16x32_bf16(pf, vh,   yh[f], 0, 0, 0);
      y2[f] = __builtin_amdgcn_mfma_f32_16x16x32_bf16(pf, ones, y2[f], 0, 0, 0);
    }
  }

  // merge the 4 key quarters (R12 epilogue)
  if (l16 == 0) {
#pragma unroll
    for (int f = 0; f < 4; ++f)
#pragma unroll
      for (int r = 0; r < 4; ++r)
        smL[wv][f * 16 + quad * 4 + r] = y2[f][r];   // cols identical
  }
  if (wv > 0) {
    int pi = wv - 1;
#pragma unroll
    for (int f = 0; f < 4; ++f)
#pragma unroll
      for (int r = 0; r < 4; ++r) {
        int lr = f * 16 + quad * 4 + r;
        smY[pi][lr][l16] = ya[f][r];
        smY[pi][lr][16 + l16] = yh[f][r];
      }
  }
  __syncthreads();
  if (wv == 0) {
    // merge + normalize; final y-tile lands in smY[0] (each thread reads
    // then overwrites ONLY its own (row,col) slots -> no cross-thread hazard)
#pragma unroll
    for (int f = 0; f < 4; ++f)
#pragma unroll
      for (int r = 0; r < 4; ++r) {
        int lr = f * 16 + quad * 4 + r;
        float a0 = ya[f][r] + smY[0][lr][l16] + smY[1][lr][l16] + smY[2][lr][l16];
        float a1 = yh[f][r] + smY[0][lr][16 + l16] + smY[1][lr][16 + l16] + smY[2][lr][16 + l16];
        float L = smL[0][lr] + smL[1][lr] + smL[2][lr] + smL[3][lr];
        float inv = 1.f / L;
        smY[0][lr][l16] = a0 * inv;
        smY[0][lr][16 + l16] = a1 * inv;
      }
  }
  __syncthreads();

  // ---- fused output conv (32->64) + bias + residual (replaces conv_out) ----
  {
    int px = lane;                       // pixel within block 0..63
    float yv[C2];
#pragma unroll
    for (int c = 0; c < C2; ++c) yv[c] = smY[0][px][c];
    const float* xb = x + (size_t)bz * Cin * HW + qrow0 + px;
    float* ob = out + (size_t)bz * Cin * HW + qrow0 + px;
#pragma unroll
    for (int i = 0; i < 16; ++i) {
      int co = wv * 16 + i;              // wave-uniform -> w_out via s_load
      float s = b_out[co];
#pragma unroll
      for (int o = 0; o < C2; ++o) s = fmaf(w_out[co * C2 + o], yv[o], s);
      ob[(size_t)co * HW] = s + xb[(size_t)co * HW];
    }
  }
}

// ---------------------------------------------------------------------------
extern "C" void kernel_launch(void* const* d_in, const int* in_sizes, int n_in,
                              void* d_out, int out_size, void* d_ws, size_t ws_size,
                              hipStream_t stream) {
  const float* x       = (const float*)d_in[0];
  const float* w_theta = (const float*)d_in[1];
  const float* b_theta = (const float*)d_in[2];
  const float* w_phi   = (const float*)d_in[3];
  const float* b_phi   = (const float*)d_in[4];
  const float* w_g     = (const float*)d_in[5];
  const float* b_g     = (const float*)d_in[6];
  const float* w_out   = (const float*)d_in[7];
  const float* b_out   = (const float*)d_in[8];
  float* out = (float*)d_out;

  float* Yws = (float*)d_ws;                                   // (unused now)
  unsigned short* Qb = (unsigned short*)(Yws + (size_t)4 * HW * C2);
  unsigned short* Kb = Qb + (size_t)4 * HW * C2;
  unsigned short* Vt = Kb + (size_t)4 * HW4 * C2;
  float* wAll = (float*)(Vt + (size_t)4 * HW4 * C2);           // 6144 f
  float* bAll = wAll + 6144;                                   // 96 f

  repack_w_kern<<<25, 256, 0, stream>>>(w_theta, b_theta, w_phi, b_phi,
                                        w_g, b_g, wAll, bAll);
  conv_qkv_kern<<<dim3(64, 4, 4), 256, 0, stream>>>(x, wAll, bAll, Qb, Kb, Vt);
  attn_mfma_kern<<<dim3(HW / 64, 4), 256, 0, stream>>>(Qb, Kb, Vt, x,
                                                       w_out, b_out, out);
}